// Round 10
// baseline (2082.235 us; speedup 1.0000x reference)
//
#include <hip/hip_runtime.h>
#include <hip/hip_fp16.h>

// ---------------------------------------------------------------------------
// 2-layer tanh RNN, B=256, T=512, H=512, D=64, + FC(512->1).
// Round 14: REVERT to round-5 build (1493us, passing) + scratch-only M=16
// differential diagnostic (T=32) whose result is encoded in kernel TIMING:
//   flags bit0 (proj0-m16 mismatch) -> +~400us spin
//   flags bit1 (rec-m16  mismatch)  -> +~200us spin
// The real output path is byte-identical to round 5. The diagnostic runs the
// r8 M=16 machinery (VALU-built A-frags + inline-asm MFMA, XOR-swizzled hbuf,
// TAILVAL epilogue) against snapshots of the trusted path; math is bitwise-
// identical per batch (same pack, same MFMA order), so tolerance is tight.
// ---------------------------------------------------------------------------

typedef _Float16 h8 __attribute__((ext_vector_type(8)));
typedef float    f4 __attribute__((ext_vector_type(4)));
typedef unsigned long long u64;

#define HID   512
#define TSEQ  512
#define NB    256
#define NWAVE 8
#define NAG   32
#define NVG   14
#define NREGF (NAG + NVG)   // 46
#define NLDSF 18
#define DT    32            // diagnostic steps

#define MFMA_A(accv, av, bv) \
  asm("v_mfma_f32_16x16x32_f16 %0, %1, %2, %0" : "+v"(accv) : "v"(av), "a"(bv))
#define MFMA_V(accv, av, bv) \
  asm("v_mfma_f32_16x16x32_f16 %0, %1, %2, %0" : "+v"(accv) : "v"(av), "v"(bv))
#define MFMA_FENCE4(a0, a1, a2, a3) \
  asm volatile("s_nop 7\n\ts_nop 7\n\ts_nop 7\n\ts_nop 7" \
               : "+v"(a0), "+v"(a1), "+v"(a2), "+v"(a3))
#define AFRAG_FENCE(av) asm volatile("s_nop 1" : "+v"(av))

#if __has_builtin(__builtin_amdgcn_rcpf)
#define FAST_RCP(x) __builtin_amdgcn_rcpf(x)
#else
#define FAST_RCP(x) (1.0f / (x))
#endif

// ---------------- workspace layout (bytes) ----------------
static const size_t OFF_P   = 0;                       // [131072][512] fp16
static const size_t OFF_B0  = 134217728;
static const size_t OFF_B1  = OFF_B0 + 65536;
static const size_t OFF_R0  = OFF_B1 + 524288;
static const size_t OFF_L0  = OFF_R0 + 376832;
static const size_t OFF_R1  = OFF_L0 + 147456;
static const size_t OFF_L1  = OFF_R1 + 376832;
static const size_t OFF_BS0 = OFF_L1 + 147456;
static const size_t OFF_BS1 = OFF_BS0 + 2048;
// --- diagnostic region ---
static const size_t OFF_PWM = OFF_BS1 + 2048;          // pack W_ih0 m16   65536
static const size_t OFF_FLG = OFF_PWM + 65536;         // int flags        4096
static const size_t OFF_S1  = OFF_FLG + 4096;          // xp0 snapshot   8388608
static const size_t OFF_S2  = OFF_S1 + 8388608;        // h1 snapshot    8388608
static const size_t OFF_X0M = OFF_S2 + 8388608;        // m16 xp0/repack 8388608
static const size_t OFF_H1M = OFF_X0M + 8388608;       // m16 h1         8388608
// total ~169.5 MB

// ---------------- prep kernels ----------------
__global__ void bias_kernel(const float* __restrict__ bih0, const float* __restrict__ bhh0,
                            const float* __restrict__ bih1, const float* __restrict__ bhh1,
                            float* __restrict__ bias0, float* __restrict__ bias1,
                            int* __restrict__ flags) {
  int i = threadIdx.x;  // block 512
  bias0[i] = bih0[i] + bhh0[i];
  bias1[i] = bih1[i] + bhh1[i];
  if (i < 16) flags[i] = 0;
}

__global__ void cvt_half_kernel(const float* __restrict__ in, _Float16* __restrict__ outp, int n) {
  int i = blockIdx.x * 256 + threadIdx.x;
  if (i < n) outp[i] = (_Float16)in[i];
}

// Pack W_hh into MFMA B-fragment order (round-5-proven layout).
__global__ void pack_rec_kernel(const float* __restrict__ W, uint4* __restrict__ BregP,
                                uint4* __restrict__ BldsP) {
  int t = blockIdx.x * 256 + threadIdx.x;
  int l  = t & 63;
  int g  = (t >> 6) & 3;
  int kk = (t >> 8) & 15;
  int w  = (t >> 12) & 7;
  int n  = 64 * w + 16 * g + (l & 15);
  int k0 = 32 * kk + ((l >> 4) & 3) * 8;
  const float* src = W + (size_t)n * HID + k0;
  h8 v;
#pragma unroll
  for (int i = 0; i < 8; ++i) v[i] = (_Float16)src[i];
  uint4 u = __builtin_bit_cast(uint4, v);
  if (g < 2) {
    BregP[(w * NREGF + 2 * kk + g) * 64 + l] = u;
  } else if (g == 2) {
    if (kk < 14) BregP[(w * NREGF + NAG + kk) * 64 + l] = u;
    else         BldsP[(w * NLDSF + 16 + (kk - 14)) * 64 + l] = u;
  } else {
    BldsP[(w * NLDSF + kk) * 64 + l] = u;
  }
}

// Pack W_ih0 for the m16 proj diagnostic.
__global__ void pack_ih0_kernel(const float* __restrict__ W, uint4* __restrict__ BP) {
  int t = blockIdx.x * 256 + threadIdx.x;   // 4096 threads
  int l = t & 63;
  int slot = (t >> 6) & 7;
  int w = (t >> 9) & 7;
  int g4 = slot & 3, kk2 = slot >> 2;
  int n  = 64 * w + 16 * g4 + (l & 15);
  int k0 = 32 * kk2 + ((l >> 4) & 3) * 8;
  const float* src = W + (size_t)n * 64 + k0;
  h8 v;
#pragma unroll
  for (int i = 0; i < 8; ++i) v[i] = (_Float16)src[i];
  BP[(w * 8 + slot) * 64 + l] = __builtin_bit_cast(uint4, v);
}

// ---------------- projection GEMM (trusted path) ----------------
template <typename AT, int K>
__global__ __launch_bounds__(256, 2) void proj_kernel(const AT* A, const _Float16* __restrict__ Bw,
                                                      _Float16* C, const float* __restrict__ bias) {
  __shared__ _Float16 At[64][40];
  __shared__ _Float16 Bt[512][40];
  const int tid = threadIdx.x;
  const int m0 = blockIdx.x * 64;
  const int wv = tid >> 6;
  const int l = tid & 63;
  const int n0 = wv * 128;
  const int lm = l & 15;
  const int lq = l >> 4;

  f4 acc[4][8];
#pragma unroll
  for (int i = 0; i < 4; ++i)
#pragma unroll
    for (int j = 0; j < 8; ++j) acc[i][j] = (f4){0.f, 0.f, 0.f, 0.f};

  const int arow = tid >> 2;
  const int kq = (tid & 3) * 8;

  for (int k0 = 0; k0 < K; k0 += 32) {
    if (sizeof(AT) == 4) {
      const float* ap = (const float*)A + (size_t)(m0 + arow) * K + k0 + kq;
      h8 v;
#pragma unroll
      for (int i = 0; i < 8; ++i) v[i] = (_Float16)ap[i];
      *(h8*)&At[arow][kq] = v;
    } else {
      *(h8*)&At[arow][kq] = *(const h8*)((const _Float16*)A + (size_t)(m0 + arow) * K + k0 + kq);
    }
#pragma unroll
    for (int rr = 0; rr < 8; ++rr) {
      int rrow = arow + rr * 64;
      *(h8*)&Bt[rrow][kq] = *(const h8*)(Bw + (size_t)rrow * K + k0 + kq);
    }
    __syncthreads();
    h8 af[4];
#pragma unroll
    for (int mm = 0; mm < 4; ++mm) af[mm] = *(const h8*)&At[mm * 16 + lm][lq * 8];
#pragma unroll
    for (int nn = 0; nn < 8; ++nn) {
      h8 bf = *(const h8*)&Bt[n0 + nn * 16 + lm][lq * 8];
#pragma unroll
      for (int mm = 0; mm < 4; ++mm)
        acc[mm][nn] = __builtin_amdgcn_mfma_f32_16x16x32_f16(af[mm], bf, acc[mm][nn], 0, 0, 0);
    }
    __syncthreads();
  }
#pragma unroll
  for (int nn = 0; nn < 8; ++nn) {
    int col = n0 + nn * 16 + lm;
    float bv = bias[col];
#pragma unroll
    for (int mm = 0; mm < 4; ++mm) {
#pragma unroll
      for (int r = 0; r < 4; ++r) {
        int row = m0 + mm * 16 + lq * 4 + r;
        C[(size_t)row * HID + col] = (_Float16)(acc[mm][nn][r] + bv);
      }
    }
  }
}

// ---------------- recurrence kernel (trusted path, round-5 verbatim) --------
template <bool WRITE_H, bool DO_FC>
__global__ __launch_bounds__(512, 2) void rec_kernel(
    const _Float16* __restrict__ P, _Float16* __restrict__ Pout,
    const uint4* __restrict__ BregP, const uint4* __restrict__ BldsP,
    const float* __restrict__ Wfc, const float* __restrict__ bfc, float* __restrict__ out) {
  __shared__ __align__(16) uint4 Blds[NWAVE * NLDSF * 64];  // 147456 B
  __shared__ __align__(16) _Float16 hbuf[2][HID];
  __shared__ float red[NWAVE];
  const int tid = threadIdx.x;
  const int b = blockIdx.x;
  const int w = tid >> 6, l = tid & 63, lq = l >> 4;

  h8 breg_a[NAG];
#pragma unroll
  for (int i = 0; i < NAG; ++i)
    breg_a[i] = __builtin_bit_cast(h8, BregP[(w * NREGF + i) * 64 + l]);
  h8 breg_v[NVG];
#pragma unroll
  for (int i = 0; i < NVG; ++i)
    breg_v[i] = __builtin_bit_cast(h8, BregP[(w * NREGF + NAG + i) * 64 + l]);
#pragma unroll
  for (int j = 0; j < NLDSF; ++j)
    Blds[(w * NLDSF + j) * 64 + l] = BldsP[(w * NLDSF + j) * 64 + l];

  ((unsigned short*)hbuf[0])[tid] = 0;
  __syncthreads();

  const _Float16* prow = P + (size_t)b * TSEQ * HID;
  unsigned short xp_cur = *(const unsigned short*)(prow + tid);
  float lv = 0.f;

#pragma unroll 1
  for (int t = 0; t < TSEQ; ++t) {
    int tn = (t + 1 < TSEQ) ? t + 1 : t;
    unsigned short xp_next = *(const unsigned short*)(prow + (size_t)tn * HID + tid);
    const _Float16* hb = hbuf[t & 1];

    f4 acc[4];
#pragma unroll
    for (int g = 0; g < 4; ++g) acc[g] = (f4){0.f, 0.f, 0.f, 0.f};

#pragma unroll
    for (int kk = 0; kk < 16; ++kk) {
      h8 a = *(const h8*)(hb + kk * 32 + lq * 8);
      MFMA_A(acc[0], a, breg_a[2 * kk]);
      MFMA_A(acc[1], a, breg_a[2 * kk + 1]);
      if (kk < 14) {
        MFMA_V(acc[2], a, breg_v[kk]);
      } else {
        h8 bf = __builtin_bit_cast(h8, Blds[(w * NLDSF + 16 + (kk - 14)) * 64 + l]);
        MFMA_V(acc[2], a, bf);
      }
      {
        h8 bf = __builtin_bit_cast(h8, Blds[(w * NLDSF + kk) * 64 + l]);
        MFMA_V(acc[3], a, bf);
      }
    }

    float hr = (lq == 0) ? acc[0][0]
             : (lq == 1) ? acc[1][0]
             : (lq == 2) ? acc[2][0]
                         : acc[3][0];

    float sum = hr + (float)__builtin_bit_cast(_Float16, xp_cur);
    float ev = __expf(2.0f * sum);
    float v = 1.0f - 2.0f * FAST_RCP(ev + 1.0f);
    lv = v;
    _Float16 hw = (_Float16)v;
    *(_Float16*)(&hbuf[(t + 1) & 1][tid]) = hw;
    if (WRITE_H)
      *(Pout + (size_t)b * TSEQ * HID + (size_t)t * HID + tid) = hw;
    __syncthreads();
    xp_cur = xp_next;
  }

  if (DO_FC) {
    float fc = lv * Wfc[tid];
#pragma unroll
    for (int off = 32; off; off >>= 1) fc += __shfl_down(fc, off, 64);
    if (l == 0) red[w] = fc;
    __syncthreads();
    if (tid == 0) {
      float s = bfc[0];
#pragma unroll
      for (int i = 0; i < NWAVE; ++i) s += red[i];
      out[b] = s;
    }
  }
}

// ======================= DIAGNOSTIC (scratch-only) =========================
// snapshot: P[b][t<DT][:] -> S[b][t][:]
__global__ void snap_kernel(const _Float16* __restrict__ P, u64* __restrict__ S) {
  size_t I = (size_t)blockIdx.x * 256 + threadIdx.x;   // 256*DT*128 u64
  int b = (int)(I >> 12);
  int rem = (int)(I & 4095);
  int t = rem >> 7, w128 = rem & 127;
  S[I] = ((const u64*)P)[(size_t)(b * TSEQ + t) * 128 + w128];
}

// m16 proj0 (r8 machinery verbatim), t < DT only, writes thread-blocked X0m.
__global__ __launch_bounds__(512, 2) void proj0m_kernel(
    const float* __restrict__ x, const uint4* __restrict__ PW,
    const float* __restrict__ bias0, u64* __restrict__ X0m) {
  const int g = blockIdx.x & 15;
  const int c = blockIdx.x >> 4;   // DT/16 chunks
  const int tid = threadIdx.x;
  const int w = tid >> 6, l = tid & 63, lq = (l >> 4) & 3, lm = l & 15;
  h8 bw[8];
#pragma unroll
  for (int s = 0; s < 8; ++s) bw[s] = __builtin_bit_cast(h8, PW[(w * 8 + s) * 64 + l]);
  float b0v[4];
#pragma unroll
  for (int g4 = 0; g4 < 4; ++g4) b0v[g4] = bias0[64 * w + 16 * g4 + lm];
  const float* xrow = x + (size_t)(g * 16 + lm) * (TSEQ * 64);
#pragma unroll 1
  for (int t = c * 16; t < c * 16 + 16; ++t) {
    f4 acc[4];
#pragma unroll
    for (int g4 = 0; g4 < 4; ++g4) acc[g4] = (f4){0.f, 0.f, 0.f, 0.f};
#pragma unroll
    for (int kk = 0; kk < 2; ++kk) {
      const float* xp = xrow + t * 64 + kk * 32 + lq * 8;
      f4 xa = *(const f4*)xp;
      f4 xb = *(const f4*)(xp + 4);
      h8 a;
#pragma unroll
      for (int i = 0; i < 4; ++i) { a[i] = (_Float16)xa[i]; a[4 + i] = (_Float16)xb[i]; }
      AFRAG_FENCE(a);
      MFMA_V(acc[0], a, bw[kk * 4 + 0]);
      MFMA_V(acc[1], a, bw[kk * 4 + 1]);
      MFMA_V(acc[2], a, bw[kk * 4 + 2]);
      MFMA_V(acc[3], a, bw[kk * 4 + 3]);
    }
    MFMA_FENCE4(acc[0], acc[1], acc[2], acc[3]);
    u64* op = X0m + ((size_t)g * DT + t) * 2048 + tid * 4;
#pragma unroll
    for (int g4 = 0; g4 < 4; ++g4) {
      u64 q = 0;
#pragma unroll
      for (int r = 0; r < 4; ++r) {
        _Float16 hv = (_Float16)(acc[g4][r] + b0v[g4]);
        q |= (u64)__builtin_bit_cast(unsigned short, hv) << (16 * r);
      }
      op[g4] = q;
    }
  }
}

// compare thread-blocked M vs row-major snapshot S; set flag bit on mismatch
__global__ void cmpm_kernel(const u64* __restrict__ M, const u64* __restrict__ S,
                            int* __restrict__ flag, int which) {
  size_t I = (size_t)blockIdx.x * 256 + threadIdx.x;   // 16*DT*2048
  int widx = (int)(I & 2047);
  int t = (int)((I >> 11) & (DT - 1));
  int g = (int)(I >> 16);   // DT=32: stride 32*2048 = 65536
  int otid = widx >> 2, g4 = widx & 3;
  int w = otid >> 6, l = otid & 63, lq = (l >> 4) & 3, lm = l & 15;
  int col = 64 * w + 16 * g4 + lm;
  u64 v = M[I];
  int bad = 0;
#pragma unroll
  for (int r = 0; r < 4; ++r) {
    float a = (float)__builtin_bit_cast(_Float16, (unsigned short)(v >> (16 * r)));
    int b = g * 16 + lq * 4 + r;
    const _Float16* Sp = (const _Float16*)S;
    float ref = (float)Sp[((size_t)b * DT + t) * 512 + col];
    float d = fabsf(a - ref);
    if (!(d <= 0.004f)) bad = 1;
  }
  if (bad) atomicOr(flag, which);
}

// repack row-major snapshot -> thread-blocked (feeds recm with trusted data)
__global__ void repackm_kernel(const u64* __restrict__ S, u64* __restrict__ X) {
  size_t I = (size_t)blockIdx.x * 256 + threadIdx.x;
  int widx = (int)(I & 2047);
  int t = (int)((I >> 11) & (DT - 1));
  int g = (int)(I >> 16);
  int otid = widx >> 2, g4 = widx & 3;
  int w = otid >> 6, l = otid & 63, lq = (l >> 4) & 3, lm = l & 15;
  int col = 64 * w + 16 * g4 + lm;
  const _Float16* Sp = (const _Float16*)S;
  u64 q = 0;
#pragma unroll
  for (int r = 0; r < 4; ++r) {
    int b = g * 16 + lq * 4 + r;
    unsigned short hv = *(const unsigned short*)&Sp[((size_t)b * DT + t) * 512 + col];
    q |= (u64)hv << (16 * r);
  }
  X[I] = q;
}

#define TAILV(g4v, rv, accv) do {                                             \
    float xs_ = (float)__builtin_bit_cast(_Float16,                            \
        (unsigned short)(xq[(g4v)] >> (16 * (rv))));                           \
    float sv_ = accv[(rv)] + xs_;                                              \
    float ev_ = __expf(2.0f * sv_);                                            \
    float vv_ = 1.0f - 2.0f * FAST_RCP(ev_ + 1.0f);                            \
    unsigned short hb_ = __builtin_bit_cast(unsigned short, (_Float16)vv_);    \
    int bb_ = lq * 4 + (rv);                                                   \
    int nn_ = 64 * w + 16 * (g4v) + lm;                                        \
    *(unsigned short*)(hw + bb_ * 1024 + ((2 * nn_) ^ (bb_ << 4))) = hb_;      \
    oq[(g4v)] |= (u64)hb_ << (16 * (rv));                                      \
  } while (0)

// m16 recurrence (r8 MODE0 machinery verbatim), T=DT, X->H (not in place)
__global__ __launch_bounds__(512, 2) void recm_kernel(
    const u64* __restrict__ Xin, u64* __restrict__ Hout,
    const uint4* __restrict__ Rw, const uint4* __restrict__ Lw) {
  __shared__ __align__(1024) char smem[155648];
  uint4* Blds = (uint4*)smem;               // 8*15*64 uint4 = 122880 B
  char*  hbuf = smem + 122880;              // 2 x [16][512] f16 swizzled = 32768 B

  const int g = blockIdx.x;
  const u64* inr = Xin + (size_t)g * DT * 2048;
  u64* outr = Hout + (size_t)g * DT * 2048;

  const int tid = threadIdx.x;
  const int w = tid >> 6, l = tid & 63, lq = (l >> 4) & 3, lm = l & 15;

  h8 breg_a[NAG];
#pragma unroll
  for (int i = 0; i < NAG; ++i)
    breg_a[i] = __builtin_bit_cast(h8, Rw[(w * NREGF + i) * 64 + l]);
  h8 breg_v[NVG];
#pragma unroll
  for (int i = 0; i < NVG; ++i)
    breg_v[i] = __builtin_bit_cast(h8, Rw[(w * NREGF + NAG + i) * 64 + l]);
#pragma unroll
  for (int j = 0; j < 15; ++j)
    Blds[(w * 15 + j) * 64 + l] = Lw[(w * NLDSF + j) * 64 + l];
  const uint4* strmp = Lw + (w * NLDSF + 15) * 64 + l;
  h8 s0 = __builtin_bit_cast(h8, strmp[0]);    // g3 kk15
  h8 s1 = __builtin_bit_cast(h8, strmp[64]);   // g2 kk14
  h8 s2 = __builtin_bit_cast(h8, strmp[128]);  // g2 kk15

  {  // h0 = 0
    u64* hz = (u64*)hbuf;
#pragma unroll
    for (int k = 0; k < 4; ++k) hz[tid * 4 + k] = 0;
  }
  const int aswz = lm << 4;

  u64 xq[4];
  {
    const u64* ip = inr + tid * 4;
#pragma unroll
    for (int k = 0; k < 4; ++k) xq[k] = ip[k];
  }
  __syncthreads();

#pragma unroll 1
  for (int t = 0; t < DT; ++t) {
    const int cur = t & 1;
    const char* hbc = hbuf + cur * 16384 + lm * 1024;
    char* hw = hbuf + (1 - cur) * 16384;

    f4 acc[4];
#pragma unroll
    for (int g4 = 0; g4 < 4; ++g4) acc[g4] = (f4){0.f, 0.f, 0.f, 0.f};
    u64 oq[4] = {0, 0, 0, 0};

    // phase 1: acc0/acc1 (AGPR weights)
#pragma unroll
    for (int kk = 0; kk < 16; ++kk) {
      h8 a = *(const h8*)(hbc + ((kk * 64 + lq * 16) ^ aswz));
      MFMA_A(acc[0], a, breg_a[2 * kk]);
      MFMA_A(acc[1], a, breg_a[2 * kk + 1]);
    }
    u64 xqn[4] = {0, 0, 0, 0};
    if (t + 1 < DT) {
      const u64* ip = inr + (size_t)(t + 1) * 2048 + tid * 4;
#pragma unroll
      for (int k = 0; k < 4; ++k) xqn[k] = ip[k];
    }
    // phase 2: acc2/acc3, acc0/acc1 tail interleaved
#pragma unroll
    for (int kk = 0; kk < 16; ++kk) {
      h8 a = *(const h8*)(hbc + ((kk * 64 + lq * 16) ^ aswz));
      if (kk < 14)      { MFMA_V(acc[2], a, breg_v[kk]); }
      else if (kk == 14){ MFMA_V(acc[2], a, s1); }
      else              { MFMA_V(acc[2], a, s2); }
      if (kk < 15) {
        h8 bf = __builtin_bit_cast(h8, Blds[(w * 15 + kk) * 64 + l]);
        MFMA_V(acc[3], a, bf);
      } else            { MFMA_V(acc[3], a, s0); }
      if (kk & 1) {
        if (kk < 8) { TAILV(0, (kk >> 1), acc[0]); }
        else        { TAILV(1, (kk >> 1) - 4, acc[1]); }
      }
    }
    MFMA_FENCE4(acc[0], acc[1], acc[2], acc[3]);
#pragma unroll
    for (int r = 0; r < 4; ++r) TAILV(2, r, acc[2]);
#pragma unroll
    for (int r = 0; r < 4; ++r) TAILV(3, r, acc[3]);
    {
      u64* op = outr + (size_t)t * 2048 + tid * 4;
#pragma unroll
      for (int g4 = 0; g4 < 4; ++g4) op[g4] = oq[g4];
    }
#pragma unroll
    for (int k = 0; k < 4; ++k) xq[k] = xqn[k];
    __syncthreads();
  }
}

// timing-channel readout: spin per flag bit
__global__ void delay_kernel(const int* __restrict__ flags) {
  if (threadIdx.x != 0 || blockIdx.x != 0) return;
  int f = flags[0];
  long long target = 0;
  if (f & 1) target += 40000;   // proj0m mismatch  (~400us @100MHz wall)
  if (f & 2) target += 20000;   // recm mismatch    (~200us)
  if (!target) return;
  long long t0 = wall_clock64();
  for (long long i = 0; i < (1LL << 30); ++i) {
    if (wall_clock64() - t0 >= target) break;
  }
}

// ---------------- launcher ----------------
extern "C" void kernel_launch(void* const* d_in, const int* in_sizes, int n_in,
                              void* d_out, int out_size, void* d_ws, size_t ws_size,
                              hipStream_t stream) {
  const float* x    = (const float*)d_in[0];
  const float* Wih0 = (const float*)d_in[1];
  const float* Whh0 = (const float*)d_in[2];
  const float* bih0 = (const float*)d_in[3];
  const float* bhh0 = (const float*)d_in[4];
  const float* Wih1 = (const float*)d_in[5];
  const float* Whh1 = (const float*)d_in[6];
  const float* bih1 = (const float*)d_in[7];
  const float* bhh1 = (const float*)d_in[8];
  const float* Wfc  = (const float*)d_in[9];
  const float* bfc  = (const float*)d_in[10];
  float* out = (float*)d_out;
  char* ws = (char*)d_ws;

  _Float16* P  = (_Float16*)(ws + OFF_P);
  _Float16* B0 = (_Float16*)(ws + OFF_B0);
  _Float16* B1 = (_Float16*)(ws + OFF_B1);
  uint4* R0 = (uint4*)(ws + OFF_R0);
  uint4* L0 = (uint4*)(ws + OFF_L0);
  uint4* R1 = (uint4*)(ws + OFF_R1);
  uint4* L1 = (uint4*)(ws + OFF_L1);
  float* bias0 = (float*)(ws + OFF_BS0);
  float* bias1 = (float*)(ws + OFF_BS1);
  uint4* PWM = (uint4*)(ws + OFF_PWM);
  int*   flags = (int*)(ws + OFF_FLG);
  u64* S1  = (u64*)(ws + OFF_S1);
  u64* S2  = (u64*)(ws + OFF_S2);
  u64* X0M = (u64*)(ws + OFF_X0M);
  u64* H1M = (u64*)(ws + OFF_H1M);

  bias_kernel<<<1, 512, 0, stream>>>(bih0, bhh0, bih1, bhh1, bias0, bias1, flags);
  cvt_half_kernel<<<128, 256, 0, stream>>>(Wih0, B0, 512 * 64);
  cvt_half_kernel<<<1024, 256, 0, stream>>>(Wih1, B1, 512 * 512);
  pack_rec_kernel<<<128, 256, 0, stream>>>(Whh0, R0, L0);
  pack_rec_kernel<<<128, 256, 0, stream>>>(Whh1, R1, L1);
  pack_ih0_kernel<<<16, 256, 0, stream>>>(Wih0, PWM);

  // trusted path + interleaved scratch diagnostics
  proj_kernel<float, 64><<<2048, 256, 0, stream>>>(x, B0, P, bias0);
  snap_kernel<<<4096, 256, 0, stream>>>(P, S1);                       // S1 = xp0
  proj0m_kernel<<<(DT / 16) * 16, 512, 0, stream>>>(x, PWM, bias0, X0M);
  cmpm_kernel<<<4096, 256, 0, stream>>>(X0M, S1, flags, 1);

  rec_kernel<true, false><<<NB, 512, 0, stream>>>(P, P, R0, L0, nullptr, nullptr, nullptr);
  snap_kernel<<<4096, 256, 0, stream>>>(P, S2);                       // S2 = h1
  repackm_kernel<<<4096, 256, 0, stream>>>(S1, X0M);                  // trusted xp0, m16 layout
  recm_kernel<<<16, 512, 0, stream>>>(X0M, H1M, R0, L0);
  cmpm_kernel<<<4096, 256, 0, stream>>>(H1M, S2, flags, 2);

  proj_kernel<_Float16, 512><<<2048, 256, 0, stream>>>(P, B1, P, bias1);
  rec_kernel<false, true><<<NB, 512, 0, stream>>>(P, nullptr, R1, L1, Wfc, bfc, out);

  delay_kernel<<<1, 64, 0, stream>>>(flags);
}